// Round 7
// baseline (610.047 us; speedup 1.0000x reference)
//
#include <hip/hip_runtime.h>
#include <hip/hip_bf16.h>

// ---------------------------------------------------------------------------
// RESK2 4-layer GCN on MI355X — round 16.
//  Fused agg+GEMM v2 (occupancy-first): 256 threads / 64 nodes per block.
//  LDS = A-tile only (17.4KB -> 8 blocks/CU cap); B read from global
//  (L2-resident 32KB, reused by all blocks). No phase barrier: each wave
//  MFMAs its OWN 16 As rows (self-written), so waves pipeline agg->gemm
//  independently. gemm0 = r9-proven 64-row tile. CSR/lsm unchanged.
// ---------------------------------------------------------------------------

typedef __attribute__((ext_vector_type(8))) short short8;
typedef __attribute__((ext_vector_type(4))) float float4v;

#define SC_SHIFT 8              // 256 nodes per sub-chunk
#define SC_NODES 256
#define FILL_CAP 12288
#define SRC_MASK 0x1FFFF        // 17 bits (N=100000 < 131072)

static __device__ __forceinline__ float bf2f_lo(unsigned int v) {
    return __uint_as_float(v << 16);
}
static __device__ __forceinline__ float bf2f_hi(unsigned int v) {
    return __uint_as_float(v & 0xffff0000u);
}
static __device__ __forceinline__ unsigned short f2bf(float f) {
    unsigned int u = __float_as_uint(f);
    u = (u + 0x7fffu + ((u >> 16) & 1u)) >> 16;  // RNE
    return (unsigned short)u;
}
static __device__ __forceinline__ unsigned int packbf(float a, float b) {
    return (unsigned int)f2bf(a) | ((unsigned int)f2bf(b) << 16);
}
static __device__ __forceinline__ float pw_w(unsigned int pe) {
    return __uint_as_float((pe >> 17) << 16);
}

static __device__ __forceinline__ void acc8(float* acc, uint4 v, float wt) {
    acc[0] = fmaf(bf2f_lo(v.x), wt, acc[0]);
    acc[1] = fmaf(bf2f_hi(v.x), wt, acc[1]);
    acc[2] = fmaf(bf2f_lo(v.y), wt, acc[2]);
    acc[3] = fmaf(bf2f_hi(v.y), wt, acc[3]);
    acc[4] = fmaf(bf2f_lo(v.z), wt, acc[4]);
    acc[5] = fmaf(bf2f_hi(v.z), wt, acc[5]);
    acc[6] = fmaf(bf2f_lo(v.w), wt, acc[6]);
    acc[7] = fmaf(bf2f_hi(v.w), wt, acc[7]);
}
static __device__ __forceinline__ void acc4(float* acc, uint2 v, float wt) {
    acc[0] = fmaf(bf2f_lo(v.x), wt, acc[0]);
    acc[1] = fmaf(bf2f_hi(v.x), wt, acc[1]);
    acc[2] = fmaf(bf2f_lo(v.y), wt, acc[2]);
    acc[3] = fmaf(bf2f_hi(v.y), wt, acc[3]);
}

// --------------------- CSR stage 1: bucket histogram -----------------------
__global__ __launch_bounds__(256) void k_count(const int* __restrict__ tgt,
                                               int* __restrict__ chunkTot,
                                               int E, int NSC) {
    __shared__ int hist[512];
    const int tid = threadIdx.x;
    hist[tid] = 0;
    hist[tid + 256] = 0;
    __syncthreads();
#pragma unroll
    for (int r = 0; r < 4; r++) {
        int e = blockIdx.x * 4096 + r * 1024 + tid * 4;
        if (e + 3 < E) {
            int4 tv = *(const int4*)&tgt[e];
            atomicAdd(&hist[tv.x >> SC_SHIFT], 1);
            atomicAdd(&hist[tv.y >> SC_SHIFT], 1);
            atomicAdd(&hist[tv.z >> SC_SHIFT], 1);
            atomicAdd(&hist[tv.w >> SC_SHIFT], 1);
        } else {
            for (int j = 0; j < 4; j++)
                if (e + j < E) atomicAdd(&hist[tgt[e + j] >> SC_SHIFT], 1);
        }
    }
    __syncthreads();
    for (int i = tid; i < NSC; i += 256) {
        int c = hist[i];
        if (c) atomicAdd(&chunkTot[i], c);
    }
}

// --------------------- CSR stage 2: bucket prefix scan ---------------------
__global__ __launch_bounds__(512) void k_scanB(const int* __restrict__ chunkTot,
                                               int* __restrict__ chunkStart,
                                               int* __restrict__ chunkCur,
                                               int E, int NSC) {
    __shared__ int sm[512];
    const int tid = threadIdx.x;
    int v = (tid < NSC) ? chunkTot[tid] : 0;
    sm[tid] = v;
    __syncthreads();
    for (int off = 1; off < 512; off <<= 1) {
        int t = (tid >= off) ? sm[tid - off] : 0;
        __syncthreads();
        sm[tid] += t;
        __syncthreads();
    }
    int excl = sm[tid] - v;
    if (tid < NSC) {
        chunkStart[tid] = excl;
        chunkCur[tid * 32] = excl;
    }
    if (tid == 0) chunkStart[NSC] = E;
}

// --------------------- CSR stage 3: bucket into staging --------------------
__global__ __launch_bounds__(512) void k_bucket(const int* __restrict__ src,
                                                const int* __restrict__ tgt,
                                                const float* __restrict__ ew,
                                                int* __restrict__ chunkCur,
                                                unsigned int* __restrict__ st_pw,
                                                unsigned char* __restrict__ st_t8,
                                                int E) {
    __shared__ int cnt[512];
    __shared__ int rk[512];
    __shared__ int bbase[512];
    const int tid = threadIdx.x;
    cnt[tid] = 0;
    rk[tid] = 0;
    __syncthreads();

    int t16[16];
    unsigned int p16[16];
#pragma unroll
    for (int r = 0; r < 4; r++) {
        int e = blockIdx.x * 8192 + r * 2048 + tid * 4;
        if (e + 3 < E) {
            int4 tv = *(const int4*)&tgt[e];
            int4 sv = *(const int4*)&src[e];
            float4 wv = *(const float4*)&ew[e];
            t16[r * 4 + 0] = tv.x; t16[r * 4 + 1] = tv.y;
            t16[r * 4 + 2] = tv.z; t16[r * 4 + 3] = tv.w;
            p16[r * 4 + 0] = ((unsigned int)f2bf(wv.x) << 17) | (unsigned int)sv.x;
            p16[r * 4 + 1] = ((unsigned int)f2bf(wv.y) << 17) | (unsigned int)sv.y;
            p16[r * 4 + 2] = ((unsigned int)f2bf(wv.z) << 17) | (unsigned int)sv.z;
            p16[r * 4 + 3] = ((unsigned int)f2bf(wv.w) << 17) | (unsigned int)sv.w;
        } else {
            for (int j = 0; j < 4; j++) {
                int ee = e + j;
                t16[r * 4 + j] = (ee < E) ? tgt[ee] : -1;
                p16[r * 4 + j] = (ee < E)
                    ? (((unsigned int)f2bf(ew[ee]) << 17) | (unsigned int)src[ee])
                    : 0u;
            }
        }
    }
#pragma unroll
    for (int j = 0; j < 16; j++)
        if (t16[j] >= 0) atomicAdd(&cnt[t16[j] >> SC_SHIFT], 1);
    __syncthreads();
    {
        int c = cnt[tid];
        bbase[tid] = c ? atomicAdd(&chunkCur[tid * 32], c) : 0;
    }
    __syncthreads();
#pragma unroll
    for (int j = 0; j < 16; j++) {
        if (t16[j] >= 0) {
            int c = t16[j] >> SC_SHIFT;
            int pos = bbase[c] + atomicAdd(&rk[c], 1);
            st_pw[pos] = p16[j];
            st_t8[pos] = (unsigned char)(t16[j] & (SC_NODES - 1));
        }
    }
}

// --------------------- CSR stage 4: per-bucket sort ------------------------
__global__ __launch_bounds__(256) void k_fill2(const unsigned int* __restrict__ st_pw,
                                               const unsigned char* __restrict__ st_t8,
                                               const int* __restrict__ chunkStart,
                                               int* __restrict__ rowptr,
                                               unsigned int* __restrict__ perm,
                                               int N, int E, int NSC) {
    __shared__ int lhist[SC_NODES];
    __shared__ int lcur[SC_NODES];
    __shared__ unsigned int ledge[FILL_CAP];
    const int tid = threadIdx.x;
    const int b = blockIdx.x;
    const int n0 = b << SC_SHIFT;
    const int nlocal = min(SC_NODES, N - n0);
    const int sstart = chunkStart[b];
    const int send = chunkStart[b + 1];
    const int cnt = send - sstart;

    lhist[tid] = 0;
    __syncthreads();
    for (int e = sstart + tid; e < send; e += 256)
        atomicAdd(&lhist[st_t8[e]], 1);
    __syncthreads();
    int v = lhist[tid];
    __syncthreads();
    lhist[tid] = v;
    __syncthreads();
    for (int off = 1; off < 256; off <<= 1) {
        int t = (tid >= off) ? lhist[tid - off] : 0;
        __syncthreads();
        lhist[tid] += t;
        __syncthreads();
    }
    int excl = lhist[tid] - v;
    if (tid < nlocal) rowptr[n0 + tid] = sstart + excl;
    if (b == NSC - 1 && tid == 0) rowptr[N] = E;
    lcur[tid] = excl;
    __syncthreads();

    if (cnt <= FILL_CAP) {
        for (int e = sstart + tid; e < send; e += 256) {
            int lt = st_t8[e];
            int pos = atomicAdd(&lcur[lt], 1);
            ledge[pos] = st_pw[e];
        }
        __syncthreads();
        for (int i = tid; i < cnt; i += 256) perm[sstart + i] = ledge[i];
    } else {
        for (int e = sstart + tid; e < send; e += 256) {
            int lt = st_t8[e];
            int pos = atomicAdd(&lcur[lt], 1);
            perm[sstart + pos] = st_pw[e];
        }
    }
}

// ----------------------------- weight prep --------------------------------
__global__ __launch_bounds__(256) void k_wtrans_all(
    const float* __restrict__ W0, const float* __restrict__ W1,
    const float* __restrict__ W2, const float* __restrict__ W3,
    unsigned short* __restrict__ Wt0, unsigned short* __restrict__ Wt1,
    unsigned short* __restrict__ Wt2, unsigned short* __restrict__ Wt3,
    int* __restrict__ chunkTot) {
    int idx = blockIdx.x * 256 + threadIdx.x;
    if (idx < 512) chunkTot[idx] = 0;
    if (idx < 32768) {
        int c = idx >> 8, k = idx & 255;
        Wt0[idx] = f2bf(W0[k * 128 + c]);
    } else if (idx < 49152) {
        int i = idx - 32768;
        int c = i >> 7, k = i & 127;
        Wt1[i] = f2bf(W1[k * 128 + c]);
    } else if (idx < 65536) {
        int i = idx - 49152;
        int c = i >> 7, k = i & 127;
        Wt2[i] = f2bf(W2[k * 128 + c]);
    } else if (idx < 71680) {
        int i = idx - 65536;
        int c = i >> 7, k = i & 127;
        Wt3[i] = (c < 40) ? f2bf(W3[k * 40 + c]) : 0;
    }
}

// ---------------------------------------------------------------------------
// GEMM0 (r9-proven): C[N,128](bf16) = x[N,256](f32) @ Wt0[128][256] + b0.
// 64x128 tile, 4 waves, LDS-staged epilogue.
// ---------------------------------------------------------------------------
__global__ __launch_bounds__(256) void k_gemm0_mfma(const float* __restrict__ A32,
                                                    const unsigned short* __restrict__ Wt,
                                                    const float* __restrict__ bias,
                                                    unsigned short* __restrict__ C, int N) {
    const int K = 256;
    __shared__ union {
        struct {
            unsigned short As[64 * 40];
            unsigned short Bs[128 * 40];
        } s;
        unsigned short Cs[64 * 136];
    } u;
    __shared__ float bsh[128];
    const int tid = threadIdx.x;
    const int wave = tid >> 6, lane = tid & 63;
    const int quad = lane >> 4, l15 = lane & 15;
    const int rowBase = blockIdx.x * 64;

    if (tid < 128) bsh[tid] = bias[tid];

    const int r0 = tid >> 2, kc0 = tid & 3;  // A: 64 rows x 4 chunks
    const int rB1 = r0, rB2 = r0 + 64;       // Wt: 128 rows
    int rg0 = rowBase + r0;
    rg0 = rg0 < N ? rg0 : N - 1;

    uint4 pa, pb0, pb1;
    auto load_step = [&](int k0) {
        const float* ap = &A32[(size_t)rg0 * K + k0 + kc0 * 8];
        float4 f0 = *(const float4*)&ap[0];
        float4 f1 = *(const float4*)&ap[4];
        pa.x = packbf(f0.x, f0.y);
        pa.y = packbf(f0.z, f0.w);
        pa.z = packbf(f1.x, f1.y);
        pa.w = packbf(f1.z, f1.w);
        pb0 = *(const uint4*)&Wt[(size_t)rB1 * K + k0 + kc0 * 8];
        pb1 = *(const uint4*)&Wt[(size_t)rB2 * K + k0 + kc0 * 8];
    };

    const float4v z = {0.f, 0.f, 0.f, 0.f};
    float4v acc[8];
#pragma unroll
    for (int j = 0; j < 8; j++) acc[j] = z;

    load_step(0);
    for (int k0 = 0; k0 < K; k0 += 32) {
        *(uint4*)&u.s.As[r0 * 40 + kc0 * 8] = pa;
        *(uint4*)&u.s.Bs[rB1 * 40 + kc0 * 8] = pb0;
        *(uint4*)&u.s.Bs[rB2 * 40 + kc0 * 8] = pb1;
        __syncthreads();
        if (k0 + 32 < K) load_step(k0 + 32);

        short8 a = *(const short8*)&u.s.As[(wave * 16 + l15) * 40 + quad * 8];
#pragma unroll
        for (int c = 0; c < 8; c++) {
            short8 b = *(const short8*)&u.s.Bs[(c * 16 + l15) * 40 + quad * 8];
            acc[c] = __builtin_amdgcn_mfma_f32_16x16x32_bf16(b, a, acc[c], 0, 0, 0);
        }
        __syncthreads();
    }

#pragma unroll
    for (int c = 0; c < 8; c++) {
        int colBase = c * 16 + quad * 4;
        float4 bv = *(const float4*)&bsh[colBase];
        uint2 o;
        o.x = packbf(acc[c][0] + bv.x, acc[c][1] + bv.y);
        o.y = packbf(acc[c][2] + bv.z, acc[c][3] + bv.w);
        *(uint2*)&u.Cs[(wave * 16 + l15) * 136 + colBase] = o;
    }
    __syncthreads();
#pragma unroll
    for (int i = 0; i < 4; i++) {
        int flat = i * 256 + tid;       // 0..1023 uint4s
        int row = flat >> 4, q = flat & 15;
        int grow = rowBase + row;
        if (grow < N) {
            uint4 v = *(const uint4*)&u.Cs[row * 136 + q * 8];
            *(uint4*)&C[(size_t)grow * 128 + q * 8] = v;
        }
    }
}

// ---------------------------------------------------------------------------
// Fused agg + GEMM (F=128 out), v2: 256 threads / 64 nodes. LDS = As only.
// Wave aggregates its 16 nodes -> own As rows -> MFMAs them (no barrier;
// wave-internal LDS ordering). B-fragments read from global (L2-hot 32KB).
// ---------------------------------------------------------------------------
template <int SAVE_RESID>
__global__ __launch_bounds__(256) void k_agg_gemm(
    const unsigned short* __restrict__ h,
    const int* __restrict__ rowptr,
    const unsigned int* __restrict__ perm,
    const unsigned short* __restrict__ Wt,
    const float* __restrict__ bias,
    unsigned short* __restrict__ resid_out,
    unsigned short* __restrict__ C, int N) {
    __shared__ unsigned short As[64 * 136];
    __shared__ float bsh[128];
    const int tid = threadIdx.x;
    const int wave = tid >> 6, lane = tid & 63;
    const int quad = lane >> 4, l15 = lane & 15;
    const int g = lane >> 4, l = lane & 15;
    const int rowBase = blockIdx.x * 64;

    if (tid < 128) bsh[tid] = bias[tid];

    // ---- Phase A: aggregate 16 nodes (this wave's As rows) ----
    const char* hB = (const char*)h;
    const unsigned int loff = (unsigned int)l * 16u;
    for (int nn = 0; nn < 16; nn++) {
        const int nodeRow = wave * 16 + nn;
        int node = rowBase + nodeRow;
        const bool valid = node < N;
        if (!valid) node = N - 1;
        const int beg = rowptr[node], end = rowptr[node + 1];

        float acc[8] = {};
        int base = beg;
        for (; base + 16 <= end; base += 16) {
            unsigned int p0 = perm[base + g];
            unsigned int p1 = perm[base + g + 4];
            unsigned int p2 = perm[base + g + 8];
            unsigned int p3 = perm[base + g + 12];
            uint4 a0 = *(const uint4*)(hB + ((((p0 & SRC_MASK) << 8)) | loff));
            uint4 a1 = *(const uint4*)(hB + ((((p1 & SRC_MASK) << 8)) | loff));
            uint4 a2 = *(const uint4*)(hB + ((((p2 & SRC_MASK) << 8)) | loff));
            uint4 a3 = *(const uint4*)(hB + ((((p3 & SRC_MASK) << 8)) | loff));
            acc8(acc, a0, pw_w(p0));
            acc8(acc, a1, pw_w(p1));
            acc8(acc, a2, pw_w(p2));
            acc8(acc, a3, pw_w(p3));
        }
        const int rem = end - base;
        if (rem > 0) {
            const int last = end - 1;
            auto step = [&](int b4) {
                int e = b4 + g;
                unsigned int p = perm[e <= last ? e : last];
                uint4 a = *(const uint4*)(hB + ((((p & SRC_MASK) << 8)) | loff));
                float w = e <= last ? pw_w(p) : 0.f;
                acc8(acc, a, w);
            };
            step(base);
            if (rem > 4) step(base + 4);
            if (rem > 8) step(base + 8);
            if (rem > 12) step(base + 12);
        }

#pragma unroll
        for (int i = 0; i < 8; i++) {
            acc[i] += __shfl_xor(acc[i], 16);
            acc[i] += __shfl_xor(acc[i], 32);
        }

        if (g == 0) {
#pragma unroll
            for (int i = 0; i < 8; i++) acc[i] = fmaxf(acc[i], 0.f);
            uint4 o;
            o.x = packbf(acc[0], acc[1]);
            o.y = packbf(acc[2], acc[3]);
            o.z = packbf(acc[4], acc[5]);
            o.w = packbf(acc[6], acc[7]);
            *(uint4*)&As[nodeRow * 136 + l * 8] = o;
            if (SAVE_RESID && valid)
                *(uint4*)&resid_out[(size_t)node * 128 + l * 8] = o;
        }
    }

    // ---- Phase B: GEMM on own rows (no barrier needed) ----
    const float4v z = {0.f, 0.f, 0.f, 0.f};
    float4v acc0[8];
#pragma unroll
    for (int j = 0; j < 8; j++) acc0[j] = z;

#pragma unroll
    for (int k0 = 0; k0 < 128; k0 += 32) {
        short8 a = *(const short8*)&As[(wave * 16 + l15) * 136 + k0 + quad * 8];
#pragma unroll
        for (int c = 0; c < 8; c++) {
            short8 b = *(const short8*)&Wt[(c * 16 + l15) * 128 + k0 + quad * 8];
            acc0[c] = __builtin_amdgcn_mfma_f32_16x16x32_bf16(b, a, acc0[c], 0, 0, 0);
        }
    }

    // stage C into own As rows (in place, own rows only)
#pragma unroll
    for (int c = 0; c < 8; c++) {
        int colBase = c * 16 + quad * 4;
        float4 bv = *(const float4*)&bsh[colBase];
        uint2 o;
        o.x = packbf(acc0[c][0] + bv.x, acc0[c][1] + bv.y);
        o.y = packbf(acc0[c][2] + bv.z, acc0[c][3] + bv.w);
        *(uint2*)&As[(wave * 16 + l15) * 136 + colBase] = o;
    }
    __syncthreads();
    // coalesced store: 64 rows x 16 uint4 = 1024
#pragma unroll
    for (int i = 0; i < 4; i++) {
        int flat = i * 256 + tid;
        int row = flat >> 4, q = flat & 15;
        int grow = rowBase + row;
        if (grow < N) {
            uint4 v = *(const uint4*)&As[row * 136 + q * 8];
            *(uint4*)&C[(size_t)grow * 128 + q * 8] = v;
        }
    }
}

// ---------------------------------------------------------------------------
// Fused agg(+resid) + GEMM40 v2: x2 = relu(agg(h)) + resid; H40 = x2 @ Wt3.
// 256 threads / 64 nodes; As-only LDS; B3 from global; 80B packed output.
// ---------------------------------------------------------------------------
__global__ __launch_bounds__(256) void k_agg_gemm40(
    const unsigned short* __restrict__ h,
    const int* __restrict__ rowptr,
    const unsigned int* __restrict__ perm,
    const unsigned short* __restrict__ resid,
    const unsigned short* __restrict__ Wt3,
    const float* __restrict__ bias,
    unsigned short* __restrict__ C, int N) {
    __shared__ unsigned short As[64 * 136];
    __shared__ float bsh[48];
    const int tid = threadIdx.x;
    const int wave = tid >> 6, lane = tid & 63;
    const int quad = lane >> 4, l15 = lane & 15;
    const int g = lane >> 4, l = lane & 15;
    const int rowBase = blockIdx.x * 64;

    if (tid < 48) bsh[tid] = (tid < 40) ? bias[tid] : 0.f;

    // ---- Phase A ----
    const char* hB = (const char*)h;
    const unsigned int loff = (unsigned int)l * 16u;
    for (int nn = 0; nn < 16; nn++) {
        const int nodeRow = wave * 16 + nn;
        int node = rowBase + nodeRow;
        const bool valid = node < N;
        if (!valid) node = N - 1;
        const int beg = rowptr[node], end = rowptr[node + 1];

        float acc[8] = {};
        int base = beg;
        for (; base + 16 <= end; base += 16) {
            unsigned int p0 = perm[base + g];
            unsigned int p1 = perm[base + g + 4];
            unsigned int p2 = perm[base + g + 8];
            unsigned int p3 = perm[base + g + 12];
            uint4 a0 = *(const uint4*)(hB + ((((p0 & SRC_MASK) << 8)) | loff));
            uint4 a1 = *(const uint4*)(hB + ((((p1 & SRC_MASK) << 8)) | loff));
            uint4 a2 = *(const uint4*)(hB + ((((p2 & SRC_MASK) << 8)) | loff));
            uint4 a3 = *(const uint4*)(hB + ((((p3 & SRC_MASK) << 8)) | loff));
            acc8(acc, a0, pw_w(p0));
            acc8(acc, a1, pw_w(p1));
            acc8(acc, a2, pw_w(p2));
            acc8(acc, a3, pw_w(p3));
        }
        const int rem = end - base;
        if (rem > 0) {
            const int last = end - 1;
            auto step = [&](int b4) {
                int e = b4 + g;
                unsigned int p = perm[e <= last ? e : last];
                uint4 a = *(const uint4*)(hB + ((((p & SRC_MASK) << 8)) | loff));
                float w = e <= last ? pw_w(p) : 0.f;
                acc8(acc, a, w);
            };
            step(base);
            if (rem > 4) step(base + 4);
            if (rem > 8) step(base + 8);
            if (rem > 12) step(base + 12);
        }

#pragma unroll
        for (int i = 0; i < 8; i++) {
            acc[i] += __shfl_xor(acc[i], 16);
            acc[i] += __shfl_xor(acc[i], 32);
        }

        if (g == 0) {
#pragma unroll
            for (int i = 0; i < 8; i++) acc[i] = fmaxf(acc[i], 0.f);
            uint4 rv = *(const uint4*)&resid[(size_t)node * 128 + l * 8];
            acc[0] += bf2f_lo(rv.x); acc[1] += bf2f_hi(rv.x);
            acc[2] += bf2f_lo(rv.y); acc[3] += bf2f_hi(rv.y);
            acc[4] += bf2f_lo(rv.z); acc[5] += bf2f_hi(rv.z);
            acc[6] += bf2f_lo(rv.w); acc[7] += bf2f_hi(rv.w);
            uint4 o;
            o.x = packbf(acc[0], acc[1]);
            o.y = packbf(acc[2], acc[3]);
            o.z = packbf(acc[4], acc[5]);
            o.w = packbf(acc[6], acc[7]);
            *(uint4*)&As[nodeRow * 136 + l * 8] = o;
        }
    }

    // ---- Phase B: GEMM40 on own rows ----
    const float4v z = {0.f, 0.f, 0.f, 0.f};
    float4v acc0[3];
#pragma unroll
    for (int j = 0; j < 3; j++) acc0[j] = z;

#pragma unroll
    for (int k0 = 0; k0 < 128; k0 += 32) {
        short8 a = *(const short8*)&As[(wave * 16 + l15) * 136 + k0 + quad * 8];
#pragma unroll
        for (int c = 0; c < 3; c++) {
            short8 b = *(const short8*)&Wt3[(c * 16 + l15) * 128 + k0 + quad * 8];
            acc0[c] = __builtin_amdgcn_mfma_f32_16x16x32_bf16(b, a, acc0[c], 0, 0, 0);
        }
    }
    __syncthreads();  // packed staging crosses wave rows -> all reads must finish

    unsigned short* Cs = As;  // reuse as packed 80B-row staging (stride 40)
#pragma unroll
    for (int c = 0; c < 3; c++) {
        int colBase = c * 16 + quad * 4;
        if (c < 2 || quad < 2) {
            float4 bv = *(const float4*)&bsh[colBase];
            uint2 o;
            o.x = packbf(acc0[c][0] + bv.x, acc0[c][1] + bv.y);
            o.y = packbf(acc0[c][2] + bv.z, acc0[c][3] + bv.w);
            *(uint2*)&Cs[(wave * 16 + l15) * 40 + colBase] = o;
        }
    }
    __syncthreads();
#pragma unroll
    for (int i = 0; i < 2; i++) {
        int flat = i * 256 + tid;       // 0..319 uint4s (64 rows x 5)
        if (flat < 320) {
            int row = flat / 5, q = flat - row * 5;
            int grow = rowBase + row;
            if (grow < N) {
                uint4 v = *(const uint4*)&Cs[row * 40 + q * 8];
                *(uint4*)&C[(size_t)grow * 40 + q * 8] = v;
            }
        }
    }
}

// ---------------------------------------------------------------------------
// Final layer: F=40 gather over packed 80B rows, 16-lane groups; fused lsm.
// ---------------------------------------------------------------------------
__global__ __launch_bounds__(256) void k_agg40_lsm(const unsigned short* __restrict__ h,
                                                   const int* __restrict__ rowptr,
                                                   const unsigned int* __restrict__ perm,
                                                   float* __restrict__ out, int N) {
    int node = (blockIdx.x * 256 + threadIdx.x) >> 6;
    if (node >= N) return;
    const int lane = threadIdx.x & 63;
    const int g = lane >> 4, l = lane & 15;
    const int beg = rowptr[node], end = rowptr[node + 1];
    const int lc = l < 10 ? l : 0;
    const char* hB = (const char*)h;
    const unsigned int loff = (unsigned int)lc * 8u;

    float acc[4] = {};

    int base = beg;
    for (; base + 16 <= end; base += 16) {
        unsigned int p0 = perm[base + g];
        unsigned int p1 = perm[base + g + 4];
        unsigned int p2 = perm[base + g + 8];
        unsigned int p3 = perm[base + g + 12];
        uint2 a0 = *(const uint2*)(hB + ((p0 & SRC_MASK) * 80u + loff));
        uint2 a1 = *(const uint2*)(hB + ((p1 & SRC_MASK) * 80u + loff));
        uint2 a2 = *(const uint2*)(hB + ((p2 & SRC_MASK) * 80u + loff));
        uint2 a3 = *(const uint2*)(hB + ((p3 & SRC_MASK) * 80u + loff));
        acc4(acc, a0, pw_w(p0));
        acc4(acc, a1, pw_w(p1));
        acc4(acc, a2, pw_w(p2));
        acc4(acc, a3, pw_w(p3));
    }
    const int rem = end - base;
    if (rem > 0) {
        const int last = end - 1;
        auto step = [&](int b4) {
            int e = b4 + g;
            unsigned int p = perm[e <= last ? e : last];
            uint2 a = *(const uint2*)(hB + ((p & SRC_MASK) * 80u + loff));
            float w = e <= last ? pw_w(p) : 0.f;
            acc4(acc, a, w);
        };
        step(base);
        if (rem > 4) step(base + 4);
        if (rem > 8) step(base + 8);
        if (rem > 12) step(base + 12);
    }
#pragma unroll
    for (int i = 0; i < 4; i++) {
        acc[i] += __shfl_xor(acc[i], 16);
        acc[i] += __shfl_xor(acc[i], 32);
    }

    bool vf = l < 10;
    float m = vf ? fmaxf(fmaxf(acc[0], acc[1]), fmaxf(acc[2], acc[3]))
                 : -__builtin_inff();
#pragma unroll
    for (int off = 1; off < 16; off <<= 1) m = fmaxf(m, __shfl_xor(m, off));
    float s = vf ? (expf(acc[0] - m) + expf(acc[1] - m) +
                    expf(acc[2] - m) + expf(acc[3] - m))
                 : 0.f;
#pragma unroll
    for (int off = 1; off < 16; off <<= 1) s += __shfl_xor(s, off);
    float ls = m + logf(s);
    if (g == 0 && vf) {
        float4 o = make_float4(acc[0] - ls, acc[1] - ls, acc[2] - ls, acc[3] - ls);
        *(float4*)&out[(size_t)node * 40 + l * 4] = o;
    }
}

extern "C" void kernel_launch(void* const* d_in, const int* in_sizes, int n_in,
                              void* d_out, int out_size, void* d_ws, size_t ws_size,
                              hipStream_t stream) {
    const float* x  = (const float*)d_in[0];
    const int*   src = (const int*)d_in[1];
    const int*   tgt = (const int*)d_in[2];
    const float* ew  = (const float*)d_in[3];
    const float* W0 = (const float*)d_in[4];
    const float* b0 = (const float*)d_in[5];
    const float* W1 = (const float*)d_in[6];
    const float* b1 = (const float*)d_in[7];
    const float* W2 = (const float*)d_in[8];
    const float* b2 = (const float*)d_in[9];
    const float* W3 = (const float*)d_in[10];
    const float* b3 = (const float*)d_in[11];

    const int N = in_sizes[0] / 256;
    const int E = in_sizes[1];
    const int NSC = (N + SC_NODES - 1) >> SC_SHIFT;

    char* ws = (char*)d_ws;
    size_t off = 0;
    auto alloc = [&](size_t bytes) -> void* {
        void* p = ws + off;
        off = (off + bytes + 255) & ~(size_t)255;
        return p;
    };
    size_t hbytes = (size_t)N * 128 * 2;
    size_t sbytes = (size_t)E * 5 + 256;
    char* hbuf = (char*)alloc(hbytes > sbytes ? hbytes : sbytes);
    unsigned short* Hb = (unsigned short*)hbuf;     // h0, later h2
    unsigned int* st_pw = (unsigned int*)hbuf;
    unsigned char* st_t8 = (unsigned char*)(hbuf + (size_t)E * 4);
    char* buf1 = (char*)alloc((size_t)N * 128 * 2);
    unsigned short* XAb  = (unsigned short*)buf1;   // residual (saved by fused L1)
    char* buf2 = (char*)alloc((size_t)N * 128 * 2);
    unsigned short* XBb  = (unsigned short*)buf2;   // h1, later H40 (80B rows)
    unsigned short* H40b = (unsigned short*)buf2;
    int*   rowptr    = (int*)alloc((size_t)(N + 1) * 4);
    int*   chunkTot  = (int*)alloc(512 * 4);
    int*   chunkStart= (int*)alloc(520 * 4);
    int*   chunkCur  = (int*)alloc(512 * 32 * 4);
    unsigned int* perm = (unsigned int*)alloc((size_t)E * 4);
    unsigned short* Wt0 = (unsigned short*)alloc(256 * 128 * 2);
    unsigned short* Wt1 = (unsigned short*)alloc(128 * 128 * 2);
    unsigned short* Wt2 = (unsigned short*)alloc(128 * 128 * 2);
    unsigned short* Wt3 = (unsigned short*)alloc(48 * 128 * 2);
    (void)ws_size;

    float* logits = (float*)d_out;

    k_wtrans_all<<<(71680 + 255) / 256, 256, 0, stream>>>(W0, W1, W2, W3,
                                                          Wt0, Wt1, Wt2, Wt3,
                                                          chunkTot);
    k_count<<<(E + 4095) / 4096, 256, 0, stream>>>(tgt, chunkTot, E, NSC);
    k_scanB<<<1, 512, 0, stream>>>(chunkTot, chunkStart, chunkCur, E, NSC);
    k_bucket<<<(E + 8191) / 8192, 512, 0, stream>>>(src, tgt, ew, chunkCur,
                                                    st_pw, st_t8, E);
    k_fill2<<<NSC, 256, 0, stream>>>(st_pw, st_t8, chunkStart, rowptr, perm,
                                     N, E, NSC);

    const int gTile = (N + 63) / 64;
    const int gWave = (N + 3) / 4;

    // L0: x @ W0 -> h0
    k_gemm0_mfma<<<gTile, 256, 0, stream>>>(x, Wt0, b0, Hb, N);
    // L1 fused: agg(h0) -> relu -> [save XA] -> @W1 -> h1
    k_agg_gemm<1><<<gTile, 256, 0, stream>>>(Hb, rowptr, perm, Wt1, b1, XAb, XBb, N);
    // L2 fused: agg(h1) -> relu -> @W2 -> h2
    k_agg_gemm<0><<<gTile, 256, 0, stream>>>(XBb, rowptr, perm, Wt2, b2, nullptr, Hb, N);
    // L3 fused: (relu(agg(h2)) + XA) @ W3 -> H40 (80B rows)
    k_agg_gemm40<<<gTile, 256, 0, stream>>>(Hb, rowptr, perm, XAb, Wt3, b3, H40b, N);
    // final gather + log_softmax
    k_agg40_lsm<<<gWave, 256, 0, stream>>>(H40b, rowptr, perm, logits, N);
}

// Round 8
// 493.858 us; speedup vs baseline: 1.2353x; 1.2353x over previous
//
#include <hip/hip_runtime.h>
#include <hip/hip_bf16.h>

// ---------------------------------------------------------------------------
// RESK2 4-layer GCN on MI355X — round 17.
//  = round-0 baseline (490.8us measured) with ONE change: H40 packed to
//  80B rows (gemm40 epilogue + agg40_lsm addressing). Cuts agg40_lsm's
//  per-XCD L2-replication fetch floor 102->64MB and gemm40 writes -5MB.
//  GEMMs: 64-row tiles; agg128: clamped 16-edge loop (proven 61.8us).
// ---------------------------------------------------------------------------

typedef __attribute__((ext_vector_type(8))) short short8;
typedef __attribute__((ext_vector_type(4))) float float4v;

#define SC_SHIFT 8              // 256 nodes per sub-chunk
#define SC_NODES 256
#define FILL_CAP 12288
#define SRC_MASK 0x1FFFF        // 17 bits (N=100000 < 131072)

static __device__ __forceinline__ float bf2f_lo(unsigned int v) {
    return __uint_as_float(v << 16);
}
static __device__ __forceinline__ float bf2f_hi(unsigned int v) {
    return __uint_as_float(v & 0xffff0000u);
}
static __device__ __forceinline__ unsigned short f2bf(float f) {
    unsigned int u = __float_as_uint(f);
    u = (u + 0x7fffu + ((u >> 16) & 1u)) >> 16;  // RNE
    return (unsigned short)u;
}
static __device__ __forceinline__ unsigned int packbf(float a, float b) {
    return (unsigned int)f2bf(a) | ((unsigned int)f2bf(b) << 16);
}
static __device__ __forceinline__ float pw_w(unsigned int pe) {
    return __uint_as_float((pe >> 17) << 16);
}

static __device__ __forceinline__ void acc8(float* acc, uint4 v, float wt) {
    acc[0] = fmaf(bf2f_lo(v.x), wt, acc[0]);
    acc[1] = fmaf(bf2f_hi(v.x), wt, acc[1]);
    acc[2] = fmaf(bf2f_lo(v.y), wt, acc[2]);
    acc[3] = fmaf(bf2f_hi(v.y), wt, acc[3]);
    acc[4] = fmaf(bf2f_lo(v.z), wt, acc[4]);
    acc[5] = fmaf(bf2f_hi(v.z), wt, acc[5]);
    acc[6] = fmaf(bf2f_lo(v.w), wt, acc[6]);
    acc[7] = fmaf(bf2f_hi(v.w), wt, acc[7]);
}
static __device__ __forceinline__ void acc4(float* acc, uint2 v, float wt) {
    acc[0] = fmaf(bf2f_lo(v.x), wt, acc[0]);
    acc[1] = fmaf(bf2f_hi(v.x), wt, acc[1]);
    acc[2] = fmaf(bf2f_lo(v.y), wt, acc[2]);
    acc[3] = fmaf(bf2f_hi(v.y), wt, acc[3]);
}

// --------------------- CSR stage 1: bucket histogram -----------------------
__global__ __launch_bounds__(256) void k_count(const int* __restrict__ tgt,
                                               int* __restrict__ chunkTot,
                                               int E, int NSC) {
    __shared__ int hist[512];
    const int tid = threadIdx.x;
    hist[tid] = 0;
    hist[tid + 256] = 0;
    __syncthreads();
#pragma unroll
    for (int r = 0; r < 4; r++) {
        int e = blockIdx.x * 4096 + r * 1024 + tid * 4;
        if (e + 3 < E) {
            int4 tv = *(const int4*)&tgt[e];
            atomicAdd(&hist[tv.x >> SC_SHIFT], 1);
            atomicAdd(&hist[tv.y >> SC_SHIFT], 1);
            atomicAdd(&hist[tv.z >> SC_SHIFT], 1);
            atomicAdd(&hist[tv.w >> SC_SHIFT], 1);
        } else {
            for (int j = 0; j < 4; j++)
                if (e + j < E) atomicAdd(&hist[tgt[e + j] >> SC_SHIFT], 1);
        }
    }
    __syncthreads();
    for (int i = tid; i < NSC; i += 256) {
        int c = hist[i];
        if (c) atomicAdd(&chunkTot[i], c);
    }
}

// --------------------- CSR stage 2: bucket prefix scan ---------------------
__global__ __launch_bounds__(512) void k_scanB(const int* __restrict__ chunkTot,
                                               int* __restrict__ chunkStart,
                                               int* __restrict__ chunkCur,
                                               int E, int NSC) {
    __shared__ int sm[512];
    const int tid = threadIdx.x;
    int v = (tid < NSC) ? chunkTot[tid] : 0;
    sm[tid] = v;
    __syncthreads();
    for (int off = 1; off < 512; off <<= 1) {
        int t = (tid >= off) ? sm[tid - off] : 0;
        __syncthreads();
        sm[tid] += t;
        __syncthreads();
    }
    int excl = sm[tid] - v;
    if (tid < NSC) {
        chunkStart[tid] = excl;
        chunkCur[tid * 32] = excl;
    }
    if (tid == 0) chunkStart[NSC] = E;
}

// --------------------- CSR stage 3: bucket into staging --------------------
__global__ __launch_bounds__(512) void k_bucket(const int* __restrict__ src,
                                                const int* __restrict__ tgt,
                                                const float* __restrict__ ew,
                                                int* __restrict__ chunkCur,
                                                unsigned int* __restrict__ st_pw,
                                                unsigned char* __restrict__ st_t8,
                                                int E) {
    __shared__ int cnt[512];
    __shared__ int rk[512];
    __shared__ int bbase[512];
    const int tid = threadIdx.x;
    cnt[tid] = 0;
    rk[tid] = 0;
    __syncthreads();

    int t16[16];
    unsigned int p16[16];
#pragma unroll
    for (int r = 0; r < 4; r++) {
        int e = blockIdx.x * 8192 + r * 2048 + tid * 4;
        if (e + 3 < E) {
            int4 tv = *(const int4*)&tgt[e];
            int4 sv = *(const int4*)&src[e];
            float4 wv = *(const float4*)&ew[e];
            t16[r * 4 + 0] = tv.x; t16[r * 4 + 1] = tv.y;
            t16[r * 4 + 2] = tv.z; t16[r * 4 + 3] = tv.w;
            p16[r * 4 + 0] = ((unsigned int)f2bf(wv.x) << 17) | (unsigned int)sv.x;
            p16[r * 4 + 1] = ((unsigned int)f2bf(wv.y) << 17) | (unsigned int)sv.y;
            p16[r * 4 + 2] = ((unsigned int)f2bf(wv.z) << 17) | (unsigned int)sv.z;
            p16[r * 4 + 3] = ((unsigned int)f2bf(wv.w) << 17) | (unsigned int)sv.w;
        } else {
            for (int j = 0; j < 4; j++) {
                int ee = e + j;
                t16[r * 4 + j] = (ee < E) ? tgt[ee] : -1;
                p16[r * 4 + j] = (ee < E)
                    ? (((unsigned int)f2bf(ew[ee]) << 17) | (unsigned int)src[ee])
                    : 0u;
            }
        }
    }
#pragma unroll
    for (int j = 0; j < 16; j++)
        if (t16[j] >= 0) atomicAdd(&cnt[t16[j] >> SC_SHIFT], 1);
    __syncthreads();
    {
        int c = cnt[tid];
        bbase[tid] = c ? atomicAdd(&chunkCur[tid * 32], c) : 0;
    }
    __syncthreads();
#pragma unroll
    for (int j = 0; j < 16; j++) {
        if (t16[j] >= 0) {
            int c = t16[j] >> SC_SHIFT;
            int pos = bbase[c] + atomicAdd(&rk[c], 1);
            st_pw[pos] = p16[j];
            st_t8[pos] = (unsigned char)(t16[j] & (SC_NODES - 1));
        }
    }
}

// --------------------- CSR stage 4: per-bucket sort ------------------------
__global__ __launch_bounds__(256) void k_fill2(const unsigned int* __restrict__ st_pw,
                                               const unsigned char* __restrict__ st_t8,
                                               const int* __restrict__ chunkStart,
                                               int* __restrict__ rowptr,
                                               unsigned int* __restrict__ perm,
                                               int N, int E, int NSC) {
    __shared__ int lhist[SC_NODES];
    __shared__ int lcur[SC_NODES];
    __shared__ unsigned int ledge[FILL_CAP];
    const int tid = threadIdx.x;
    const int b = blockIdx.x;
    const int n0 = b << SC_SHIFT;
    const int nlocal = min(SC_NODES, N - n0);
    const int sstart = chunkStart[b];
    const int send = chunkStart[b + 1];
    const int cnt = send - sstart;

    lhist[tid] = 0;
    __syncthreads();
    for (int e = sstart + tid; e < send; e += 256)
        atomicAdd(&lhist[st_t8[e]], 1);
    __syncthreads();
    int v = lhist[tid];
    __syncthreads();
    lhist[tid] = v;
    __syncthreads();
    for (int off = 1; off < 256; off <<= 1) {
        int t = (tid >= off) ? lhist[tid - off] : 0;
        __syncthreads();
        lhist[tid] += t;
        __syncthreads();
    }
    int excl = lhist[tid] - v;
    if (tid < nlocal) rowptr[n0 + tid] = sstart + excl;
    if (b == NSC - 1 && tid == 0) rowptr[N] = E;
    lcur[tid] = excl;
    __syncthreads();

    if (cnt <= FILL_CAP) {
        for (int e = sstart + tid; e < send; e += 256) {
            int lt = st_t8[e];
            int pos = atomicAdd(&lcur[lt], 1);
            ledge[pos] = st_pw[e];
        }
        __syncthreads();
        for (int i = tid; i < cnt; i += 256) perm[sstart + i] = ledge[i];
    } else {
        for (int e = sstart + tid; e < send; e += 256) {
            int lt = st_t8[e];
            int pos = atomicAdd(&lcur[lt], 1);
            perm[sstart + pos] = st_pw[e];
        }
    }
}

// ----------------------------- weight prep --------------------------------
__global__ __launch_bounds__(256) void k_wtrans_all(
    const float* __restrict__ W0, const float* __restrict__ W1,
    const float* __restrict__ W2, const float* __restrict__ W3,
    unsigned short* __restrict__ Wt0, unsigned short* __restrict__ Wt1,
    unsigned short* __restrict__ Wt2, unsigned short* __restrict__ Wt3,
    int* __restrict__ chunkTot) {
    int idx = blockIdx.x * 256 + threadIdx.x;
    if (idx < 512) chunkTot[idx] = 0;
    if (idx < 32768) {
        int c = idx >> 8, k = idx & 255;
        Wt0[idx] = f2bf(W0[k * 128 + c]);
    } else if (idx < 49152) {
        int i = idx - 32768;
        int c = i >> 7, k = i & 127;
        Wt1[i] = f2bf(W1[k * 128 + c]);
    } else if (idx < 65536) {
        int i = idx - 49152;
        int c = i >> 7, k = i & 127;
        Wt2[i] = f2bf(W2[k * 128 + c]);
    } else if (idx < 71680) {
        int i = idx - 65536;
        int c = i >> 7, k = i & 127;
        Wt3[i] = (c < 40) ? f2bf(W3[k * 40 + c]) : 0;
    }
}

// ---------------------------------------------------------------------------
// MFMA GEMM: C[N,128](bf16) = A[N,K] @ Wt[128][K] + b. 64x128 tile/block,
// 4 waves, wave = 16 rows x 128 cols. Swapped operands: lane holds
// C[row=l15][cols quad*4..+3] per c-tile. Epilogue staged through LDS ->
// full-line uint4 stores.
// ---------------------------------------------------------------------------
template <int K, int AF32>
__global__ __launch_bounds__(256) void k_gemm_mfma(const void* __restrict__ Av,
                                                   const unsigned short* __restrict__ Wt,
                                                   const float* __restrict__ bias,
                                                   unsigned short* __restrict__ C, int N) {
    __shared__ union {
        struct {
            unsigned short As[64 * 40];
            unsigned short Bs[128 * 40];
        } s;
        unsigned short Cs[64 * 136];  // epilogue staging, stride 136 (272B = 17x16B)
    } u;
    __shared__ float bsh[128];
    const unsigned short* A16 = (const unsigned short*)Av;
    const float* A32 = (const float*)Av;
    const int tid = threadIdx.x;
    const int wave = tid >> 6, lane = tid & 63;
    const int quad = lane >> 4, l15 = lane & 15;
    const int rowBase = blockIdx.x * 64;

    if (tid < 128) bsh[tid] = bias[tid];

    const int r0 = tid >> 2, kc0 = tid & 3;  // A: 64 rows x 4 chunks
    const int rB1 = r0, rB2 = r0 + 64;       // Wt: 128 rows
    int rg0 = rowBase + r0;
    rg0 = rg0 < N ? rg0 : N - 1;

    uint4 pa, pb0, pb1;
    auto load_step = [&](int k0) {
        if (AF32) {
            float4 f0 = *(const float4*)&A32[(size_t)rg0 * K + k0 + kc0 * 8];
            float4 f1 = *(const float4*)&A32[(size_t)rg0 * K + k0 + kc0 * 8 + 4];
            pa.x = packbf(f0.x, f0.y);
            pa.y = packbf(f0.z, f0.w);
            pa.z = packbf(f1.x, f1.y);
            pa.w = packbf(f1.z, f1.w);
        } else {
            pa = *(const uint4*)&A16[(size_t)rg0 * K + k0 + kc0 * 8];
        }
        pb0 = *(const uint4*)&Wt[(size_t)rB1 * K + k0 + kc0 * 8];
        pb1 = *(const uint4*)&Wt[(size_t)rB2 * K + k0 + kc0 * 8];
    };

    const float4v z = {0.f, 0.f, 0.f, 0.f};
    float4v acc[8];
#pragma unroll
    for (int j = 0; j < 8; j++) acc[j] = z;

    load_step(0);
    for (int k0 = 0; k0 < K; k0 += 32) {
        *(uint4*)&u.s.As[r0 * 40 + kc0 * 8] = pa;
        *(uint4*)&u.s.Bs[rB1 * 40 + kc0 * 8] = pb0;
        *(uint4*)&u.s.Bs[rB2 * 40 + kc0 * 8] = pb1;
        __syncthreads();
        if (k0 + 32 < K) load_step(k0 + 32);  // prefetch overlaps compute

        short8 a = *(const short8*)&u.s.As[(wave * 16 + l15) * 40 + quad * 8];
#pragma unroll
        for (int c = 0; c < 8; c++) {
            short8 b = *(const short8*)&u.s.Bs[(c * 16 + l15) * 40 + quad * 8];
            acc[c] = __builtin_amdgcn_mfma_f32_16x16x32_bf16(b, a, acc[c], 0, 0, 0);
        }
        __syncthreads();
    }

    // stage C tile (64x128 bf16) into LDS, then full-line stores
#pragma unroll
    for (int c = 0; c < 8; c++) {
        int colBase = c * 16 + quad * 4;
        float4 bv = *(const float4*)&bsh[colBase];
        uint2 o;
        o.x = packbf(acc[c][0] + bv.x, acc[c][1] + bv.y);
        o.y = packbf(acc[c][2] + bv.z, acc[c][3] + bv.w);
        *(uint2*)&u.Cs[(wave * 16 + l15) * 136 + colBase] = o;
    }
    __syncthreads();
#pragma unroll
    for (int i = 0; i < 4; i++) {
        int flat = i * 256 + tid;       // 0..1023 uint4s
        int row = flat >> 4, q = flat & 15;
        int grow = rowBase + row;
        if (grow < N) {
            uint4 v = *(const uint4*)&u.Cs[row * 136 + q * 8];
            *(uint4*)&C[(size_t)grow * 128 + q * 8] = v;
        }
    }
}

// MFMA gemm40: H40[N,40-stride](bf16) = A[N,128](bf16) @ Wt3[48][128] + b3.
// 64-row tile; output rows PACKED to 80B (5x16B) -> smaller gather array.
__global__ __launch_bounds__(256) void k_gemm40_mfma(const unsigned short* __restrict__ A,
                                                     const unsigned short* __restrict__ Wt3,
                                                     const float* __restrict__ bias,
                                                     unsigned short* __restrict__ C, int N) {
    __shared__ union {
        struct {
            unsigned short As[64 * 40];
            unsigned short Bs[48 * 136];
        } s;
        unsigned short Cs[64 * 40];  // packed 80B rows (5x16B)
    } u;
    __shared__ float bsh[48];
    const int tid = threadIdx.x;
    const int wave = tid >> 6, lane = tid & 63;
    const int quad = lane >> 4, l15 = lane & 15;
    const int rowBase = blockIdx.x * 64;

    if (tid < 48) bsh[tid] = (tid < 40) ? bias[tid] : 0.f;

    const int r0 = tid >> 2, kc0 = tid & 3;
    int rg0 = rowBase + r0;
    rg0 = rg0 < N ? rg0 : N - 1;

    // Bs3 staged once (survives the K loop)
    for (int t = tid; t < 48 * 16; t += 256) {
        int r = t >> 4, kc = t & 15;
        uint4 v = *(const uint4*)&Wt3[r * 128 + kc * 8];
        *(uint4*)&u.s.Bs[r * 136 + kc * 8] = v;
    }

    uint4 pa;
    auto load_step = [&](int k0) {
        pa = *(const uint4*)&A[(size_t)rg0 * 128 + k0 + kc0 * 8];
    };

    const float4v z = {0.f, 0.f, 0.f, 0.f};
    float4v acc[3];
#pragma unroll
    for (int j = 0; j < 3; j++) acc[j] = z;

    load_step(0);
    for (int k0 = 0; k0 < 128; k0 += 32) {
        *(uint4*)&u.s.As[r0 * 40 + kc0 * 8] = pa;
        __syncthreads();
        if (k0 + 32 < 128) load_step(k0 + 32);

        short8 a = *(const short8*)&u.s.As[(wave * 16 + l15) * 40 + quad * 8];
#pragma unroll
        for (int c = 0; c < 3; c++) {
            short8 b = *(const short8*)&u.s.Bs[(c * 16 + l15) * 136 + k0 + quad * 8];
            acc[c] = __builtin_amdgcn_mfma_f32_16x16x32_bf16(b, a, acc[c], 0, 0, 0);
        }
        __syncthreads();
    }

    // stage 64x40 packed tile into LDS (cols 40..47 of c=2 dropped)
#pragma unroll
    for (int c = 0; c < 3; c++) {
        int colBase = c * 16 + quad * 4;
        if (c < 2 || quad < 2) {
            float4 bv = *(const float4*)&bsh[colBase];
            uint2 o;
            o.x = packbf(acc[c][0] + bv.x, acc[c][1] + bv.y);
            o.y = packbf(acc[c][2] + bv.z, acc[c][3] + bv.w);
            *(uint2*)&u.Cs[(wave * 16 + l15) * 40 + colBase] = o;
        }
    }
    __syncthreads();
#pragma unroll
    for (int i = 0; i < 2; i++) {
        int flat = i * 256 + tid;       // 0..319 uint4s (64 rows x 5)
        if (flat < 320) {
            int row = flat / 5, q = flat - row * 5;
            int grow = rowBase + row;
            if (grow < N) {
                uint4 v = *(const uint4*)&u.Cs[row * 40 + q * 8];
                *(uint4*)&C[(size_t)grow * 40 + q * 8] = v;
            }
        }
    }
}

// ---------------------------------------------------------------------------
// Pull aggregation F=128: one wave/node, quarter-wave per edge (packed perm).
// (round-0 proven form: clamped 16-edge loop)
// ---------------------------------------------------------------------------
__global__ __launch_bounds__(256) void k_agg128(const unsigned short* __restrict__ h,
                                                const int* __restrict__ rowptr,
                                                const unsigned int* __restrict__ perm,
                                                const unsigned short* __restrict__ resid,
                                                unsigned short* __restrict__ out, int N) {
    int node = (blockIdx.x * 256 + threadIdx.x) >> 6;
    if (node >= N) return;
    const int lane = threadIdx.x & 63;
    const int g = lane >> 4, l = lane & 15;
    const int beg = rowptr[node], end = rowptr[node + 1];
    const int last = end - 1;

    float acc[8] = {};
    for (int base = beg; base < end; base += 16) {
        int e0 = base + g, e1 = base + 4 + g, e2 = base + 8 + g, e3 = base + 12 + g;
        unsigned int p0 = perm[e0 <= last ? e0 : last];
        unsigned int p1 = perm[e1 <= last ? e1 : last];
        unsigned int p2 = perm[e2 <= last ? e2 : last];
        unsigned int p3 = perm[e3 <= last ? e3 : last];
        uint4 a0 = *(const uint4*)&h[(size_t)(p0 & SRC_MASK) * 128 + l * 8];
        uint4 a1 = *(const uint4*)&h[(size_t)(p1 & SRC_MASK) * 128 + l * 8];
        uint4 a2 = *(const uint4*)&h[(size_t)(p2 & SRC_MASK) * 128 + l * 8];
        uint4 a3 = *(const uint4*)&h[(size_t)(p3 & SRC_MASK) * 128 + l * 8];
        float w0 = e0 <= last ? pw_w(p0) : 0.f;
        float w1 = e1 <= last ? pw_w(p1) : 0.f;
        float w2 = e2 <= last ? pw_w(p2) : 0.f;
        float w3 = e3 <= last ? pw_w(p3) : 0.f;
        acc8(acc, a0, w0);
        acc8(acc, a1, w1);
        acc8(acc, a2, w2);
        acc8(acc, a3, w3);
    }

#pragma unroll
    for (int i = 0; i < 8; i++) {
        acc[i] += __shfl_xor(acc[i], 16);
        acc[i] += __shfl_xor(acc[i], 32);
    }

    if (g == 0) {
#pragma unroll
        for (int i = 0; i < 8; i++) acc[i] = fmaxf(acc[i], 0.f);
        if (resid) {
            uint4 rv = *(const uint4*)&resid[(size_t)node * 128 + l * 8];
            acc[0] += bf2f_lo(rv.x); acc[1] += bf2f_hi(rv.x);
            acc[2] += bf2f_lo(rv.y); acc[3] += bf2f_hi(rv.y);
            acc[4] += bf2f_lo(rv.z); acc[5] += bf2f_hi(rv.z);
            acc[6] += bf2f_lo(rv.w); acc[7] += bf2f_hi(rv.w);
        }
        uint4 o;
        o.x = packbf(acc[0], acc[1]);
        o.y = packbf(acc[2], acc[3]);
        o.z = packbf(acc[4], acc[5]);
        o.w = packbf(acc[6], acc[7]);
        *(uint4*)&out[(size_t)node * 128 + l * 8] = o;
    }
}

// ---------------------------------------------------------------------------
// Final layer: F=40 gather over PACKED 80B rows, 16-lane groups; fused lsm.
// ---------------------------------------------------------------------------
__global__ __launch_bounds__(256) void k_agg40_lsm(const unsigned short* __restrict__ h,
                                                   const int* __restrict__ rowptr,
                                                   const unsigned int* __restrict__ perm,
                                                   float* __restrict__ out, int N) {
    int node = (blockIdx.x * 256 + threadIdx.x) >> 6;
    if (node >= N) return;
    const int lane = threadIdx.x & 63;
    const int g = lane >> 4, l = lane & 15;
    const int beg = rowptr[node], end = rowptr[node + 1];
    const int last = end - 1;
    const int lc = l < 10 ? l : 0;
    const char* hB = (const char*)h;
    const unsigned int loff = (unsigned int)lc * 8u;  // byte offset within 80B row

    float acc[4] = {};
    for (int base = beg; base < end; base += 16) {
        int e0 = base + g, e1 = base + 4 + g, e2 = base + 8 + g, e3 = base + 12 + g;
        unsigned int p0 = perm[e0 <= last ? e0 : last];
        unsigned int p1 = perm[e1 <= last ? e1 : last];
        unsigned int p2 = perm[e2 <= last ? e2 : last];
        unsigned int p3 = perm[e3 <= last ? e3 : last];
        uint2 a0 = *(const uint2*)(hB + (p0 & SRC_MASK) * 80u + loff);
        uint2 a1 = *(const uint2*)(hB + (p1 & SRC_MASK) * 80u + loff);
        uint2 a2 = *(const uint2*)(hB + (p2 & SRC_MASK) * 80u + loff);
        uint2 a3 = *(const uint2*)(hB + (p3 & SRC_MASK) * 80u + loff);
        float w0 = e0 <= last ? pw_w(p0) : 0.f;
        float w1 = e1 <= last ? pw_w(p1) : 0.f;
        float w2 = e2 <= last ? pw_w(p2) : 0.f;
        float w3 = e3 <= last ? pw_w(p3) : 0.f;
        acc4(acc, a0, w0);
        acc4(acc, a1, w1);
        acc4(acc, a2, w2);
        acc4(acc, a3, w3);
    }
#pragma unroll
    for (int i = 0; i < 4; i++) {
        acc[i] += __shfl_xor(acc[i], 16);
        acc[i] += __shfl_xor(acc[i], 32);
    }

    bool vf = l < 10;
    float m = vf ? fmaxf(fmaxf(acc[0], acc[1]), fmaxf(acc[2], acc[3]))
                 : -__builtin_inff();
#pragma unroll
    for (int off = 1; off < 16; off <<= 1) m = fmaxf(m, __shfl_xor(m, off));
    float s = vf ? (expf(acc[0] - m) + expf(acc[1] - m) +
                    expf(acc[2] - m) + expf(acc[3] - m))
                 : 0.f;
#pragma unroll
    for (int off = 1; off < 16; off <<= 1) s += __shfl_xor(s, off);
    float ls = m + logf(s);
    if (g == 0 && vf) {
        float4 o = make_float4(acc[0] - ls, acc[1] - ls, acc[2] - ls, acc[3] - ls);
        *(float4*)&out[(size_t)node * 40 + l * 4] = o;
    }
}

extern "C" void kernel_launch(void* const* d_in, const int* in_sizes, int n_in,
                              void* d_out, int out_size, void* d_ws, size_t ws_size,
                              hipStream_t stream) {
    const float* x  = (const float*)d_in[0];
    const int*   src = (const int*)d_in[1];
    const int*   tgt = (const int*)d_in[2];
    const float* ew  = (const float*)d_in[3];
    const float* W0 = (const float*)d_in[4];
    const float* b0 = (const float*)d_in[5];
    const float* W1 = (const float*)d_in[6];
    const float* b1 = (const float*)d_in[7];
    const float* W2 = (const float*)d_in[8];
    const float* b2 = (const float*)d_in[9];
    const float* W3 = (const float*)d_in[10];
    const float* b3 = (const float*)d_in[11];

    const int N = in_sizes[0] / 256;
    const int E = in_sizes[1];
    const int NSC = (N + SC_NODES - 1) >> SC_SHIFT;

    char* ws = (char*)d_ws;
    size_t off = 0;
    auto alloc = [&](size_t bytes) -> void* {
        void* p = ws + off;
        off = (off + bytes + 255) & ~(size_t)255;
        return p;
    };
    unsigned short* XCb = (unsigned short*)alloc((size_t)N * 128 * 2);
    size_t hbytes = (size_t)N * 128 * 2;
    size_t sbytes = (size_t)E * 5 + 256;
    char* hbuf = (char*)alloc(hbytes > sbytes ? hbytes : sbytes);
    unsigned short* Hb = (unsigned short*)hbuf;
    unsigned int* st_pw = (unsigned int*)hbuf;
    unsigned char* st_t8 = (unsigned char*)(hbuf + (size_t)E * 4);
    char* buf1 = (char*)alloc((size_t)N * 128 * 2);
    unsigned short* XAb  = (unsigned short*)buf1;
    unsigned short* H40b = (unsigned short*)buf1;   // N x 40 shorts (80B rows)
    unsigned short* XBb  = (unsigned short*)alloc((size_t)N * 128 * 2);
    int*   rowptr    = (int*)alloc((size_t)(N + 1) * 4);
    int*   chunkTot  = (int*)alloc(512 * 4);
    int*   chunkStart= (int*)alloc(520 * 4);
    int*   chunkCur  = (int*)alloc(512 * 32 * 4);
    unsigned int* perm = (unsigned int*)alloc((size_t)E * 4);
    unsigned short* Wt0 = (unsigned short*)alloc(256 * 128 * 2);
    unsigned short* Wt1 = (unsigned short*)alloc(128 * 128 * 2);
    unsigned short* Wt2 = (unsigned short*)alloc(128 * 128 * 2);
    unsigned short* Wt3 = (unsigned short*)alloc(48 * 128 * 2);
    (void)ws_size;

    float* logits = (float*)d_out;

    k_wtrans_all<<<(71680 + 255) / 256, 256, 0, stream>>>(W0, W1, W2, W3,
                                                          Wt0, Wt1, Wt2, Wt3,
                                                          chunkTot);
    k_count<<<(E + 4095) / 4096, 256, 0, stream>>>(tgt, chunkTot, E, NSC);
    k_scanB<<<1, 512, 0, stream>>>(chunkTot, chunkStart, chunkCur, E, NSC);
    k_bucket<<<(E + 8191) / 8192, 512, 0, stream>>>(src, tgt, ew, chunkCur,
                                                    st_pw, st_t8, E);
    k_fill2<<<NSC, 256, 0, stream>>>(st_pw, st_t8, chunkStart, rowptr, perm,
                                     N, E, NSC);

    const int gGemm = (N + 63) / 64;
    const int gWave = (N + 3) / 4;

    // L0 (reads fp32 x directly)
    k_gemm_mfma<256, 1><<<gGemm, 256, 0, stream>>>(x, Wt0, b0, Hb, N);
    k_agg128<<<gWave, 256, 0, stream>>>(Hb, rowptr, perm, nullptr, XAb, N);
    // L1
    k_gemm_mfma<128, 0><<<gGemm, 256, 0, stream>>>(XAb, Wt1, b1, Hb, N);
    k_agg128<<<gWave, 256, 0, stream>>>(Hb, rowptr, perm, nullptr, XBb, N);
    // L2 (+residual XAb) -> XCb
    k_gemm_mfma<128, 0><<<gGemm, 256, 0, stream>>>(XBb, Wt2, b2, Hb, N);
    k_agg128<<<gWave, 256, 0, stream>>>(Hb, rowptr, perm, XAb, XCb, N);
    // L3 (packed 80B output rows)
    k_gemm40_mfma<<<gGemm, 256, 0, stream>>>(XCb, Wt3, b3, H40b, N);
    k_agg40_lsm<<<gWave, 256, 0, stream>>>(H40b, rowptr, perm, logits, N);
}